// Round 1
// baseline (288.541 us; speedup 1.0000x reference)
//
#include <hip/hip_runtime.h>
#include <stdint.h>

// B=2, S=2048, D=1024, H=16, HD=64
typedef unsigned short u16;
typedef __bf16 bf16x8 __attribute__((ext_vector_type(8)));
typedef float f32x4 __attribute__((ext_vector_type(4)));
typedef unsigned short u16x8 __attribute__((ext_vector_type(8)));
typedef unsigned short u16x4 __attribute__((ext_vector_type(4)));

static __device__ __forceinline__ u16 f2bf(float f) {
  unsigned u = __builtin_bit_cast(unsigned, f);
  u += 0x7fffu + ((u >> 16) & 1u);   // RNE
  return (u16)(u >> 16);
}

static __device__ __forceinline__ bf16x8 ldfrag(const u16* p) {
  return *reinterpret_cast<const bf16x8*>(p);
}

static __device__ __forceinline__ void gll16(const u16* g, u16* l) {
  __builtin_amdgcn_global_load_lds(
      (const __attribute__((address_space(1))) void*)g,
      (__attribute__((address_space(3))) void*)l, 16, 0, 0);
}

// ---------------- cast x: fp32 -> bf16, [4096][1024] ----------------
__global__ __launch_bounds__(256) void cast_x_kernel(const float* __restrict__ x,
                                                     u16* __restrict__ xb) {
  int i = (blockIdx.x * 256 + threadIdx.x) * 8;
  const float4* p = reinterpret_cast<const float4*>(x + i);
  float4 a = p[0], b = p[1];
  u16x8 o;
  o[0] = f2bf(a.x); o[1] = f2bf(a.y); o[2] = f2bf(a.z); o[3] = f2bf(a.w);
  o[4] = f2bf(b.x); o[5] = f2bf(b.y); o[6] = f2bf(b.z); o[7] = f2bf(b.w);
  *reinterpret_cast<u16x8*>(xb + i) = o;
}

// -------- transpose + cast W [k][n] fp32 -> Wt [n][k] bf16 (z picks Wq/Wk/Wv/Wo) --------
__global__ __launch_bounds__(256) void transpose_w_kernel(
    const float* __restrict__ Wq, const float* __restrict__ Wk,
    const float* __restrict__ Wv, const float* __restrict__ Wo,
    u16* __restrict__ WT) {
  __shared__ float tile[64][65];
  int z = blockIdx.z;
  const float* W = (z == 0) ? Wq : (z == 1) ? Wk : (z == 2) ? Wv : Wo;
  u16* out = WT + (size_t)z * 1024 * 1024;
  int k0 = blockIdx.y * 64, n0 = blockIdx.x * 64;
  int t = threadIdx.x;
  int rr = t >> 4;         // 0..15
  int cc = (t & 15) * 4;   // 0..60
#pragma unroll
  for (int j = 0; j < 4; ++j) {
    int r = rr + 16 * j;
    float4 v = *reinterpret_cast<const float4*>(W + (size_t)(k0 + r) * 1024 + n0 + cc);
    tile[r][cc + 0] = v.x; tile[r][cc + 1] = v.y;
    tile[r][cc + 2] = v.z; tile[r][cc + 3] = v.w;
  }
  __syncthreads();
#pragma unroll
  for (int j = 0; j < 4; ++j) {
    int nl = rr + 16 * j;
    u16x4 o;
#pragma unroll
    for (int i2 = 0; i2 < 4; ++i2) o[i2] = f2bf(tile[cc + i2][nl]);
    *reinterpret_cast<u16x4*>(out + (size_t)(n0 + nl) * 1024 + k0 + cc) = o;
  }
}

// ---------------- generic bf16 GEMM: C[4096][1024] = A @ Wt^T + bias ----------------
// A: [4096][1024] bf16 row-major. Wt: [n][k] bf16 (pre-transposed W).
// MODE 0: write bf16 to [B,H,S,HD]. MODE 1: write fp32 linear [m][n].
template <int MODE>
static __device__ __forceinline__ void gemm_body(const u16* __restrict__ A,
                                                 const u16* __restrict__ Wt,
                                                 const float* __restrict__ bias,
                                                 void* __restrict__ Out) {
  __shared__ u16 As[128 * 32];
  __shared__ u16 Bs[128 * 32];
  int t = threadIdx.x;
  int lane = t & 63, wave = t >> 6;
  int g = lane >> 4, c = lane & 15;
  int m0 = blockIdx.y * 128, n0 = blockIdx.x * 128;
  int wm = (wave >> 1) * 64, wn = (wave & 1) * 64;

  f32x4 acc[4][4] = {};

  const u16* Ag = A + (size_t)(m0 + (t >> 2)) * 1024 + (t & 3) * 8;
  const u16* Bg = Wt + (size_t)(n0 + (t >> 2)) * 1024 + (t & 3) * 8;
  u16* Asd = As + t * 8;
  u16* Bsd = Bs + t * 8;

  for (int k0 = 0; k0 < 1024; k0 += 32) {
    gll16(Ag + k0, Asd);
    gll16(Ag + 64 * 1024 + k0, Asd + 64 * 32);
    gll16(Bg + k0, Bsd);
    gll16(Bg + 64 * 1024 + k0, Bsd + 64 * 32);
    __syncthreads();
    bf16x8 af[4], bfr[4];
#pragma unroll
    for (int i = 0; i < 4; ++i) {
      af[i]  = ldfrag(As + (wm + 16 * i + c) * 32 + g * 8);
      bfr[i] = ldfrag(Bs + (wn + 16 * i + c) * 32 + g * 8);
    }
#pragma unroll
    for (int i = 0; i < 4; ++i)
#pragma unroll
      for (int j = 0; j < 4; ++j)
        acc[i][j] = __builtin_amdgcn_mfma_f32_16x16x32_bf16(af[i], bfr[j], acc[i][j], 0, 0, 0);
    __syncthreads();
  }

  if (MODE == 0) {
    u16* out = (u16*)Out;
#pragma unroll
    for (int i = 0; i < 4; ++i) {
      int mb = m0 + wm + 16 * i + g * 4;
#pragma unroll
      for (int j = 0; j < 4; ++j) {
        int n = n0 + wn + 16 * j + c;
        float bv = bias[n];
        int h = n >> 6, d = n & 63;
#pragma unroll
        for (int r = 0; r < 4; ++r) {
          int m = mb + r;
          int b = m >> 11, s = m & 2047;   // m = b*2048 + s
          out[((size_t)(b * 16 + h) * 2048 + s) * 64 + d] = f2bf(acc[i][j][r] + bv);
        }
      }
    }
  } else {
    float* out = (float*)Out;
#pragma unroll
    for (int i = 0; i < 4; ++i) {
      int mb = m0 + wm + 16 * i + g * 4;
#pragma unroll
      for (int j = 0; j < 4; ++j) {
        int n = n0 + wn + 16 * j + c;
        float bv = bias[n];
#pragma unroll
        for (int r = 0; r < 4; ++r)
          out[(size_t)(mb + r) * 1024 + n] = acc[i][j][r] + bv;
      }
    }
  }
}

__global__ __launch_bounds__(256) void qkv_gemm_kernel(
    const u16* __restrict__ xb, const u16* __restrict__ WT,
    const float* __restrict__ bq, const float* __restrict__ bk,
    const float* __restrict__ bv,
    u16* __restrict__ Q, u16* __restrict__ K, u16* __restrict__ V) {
  int z = blockIdx.z;
  const u16* Wt = WT + (size_t)z * 1024 * 1024;
  const float* bias = (z == 0) ? bq : (z == 1) ? bk : bv;
  u16* out = (z == 0) ? Q : (z == 1) ? K : V;
  gemm_body<0>(xb, Wt, bias, out);
}

__global__ __launch_bounds__(256) void oproj_kernel(
    const u16* __restrict__ attnb, const u16* __restrict__ WoT,
    const float* __restrict__ bo, float* __restrict__ out) {
  gemm_body<1>(attnb, WoT, bo, out);
}

// ---------------- flash attention ----------------
// Q,K,V: [B,H,S,HD] bf16. Output attn: [B,S,D] bf16.
// Block: 4 waves, each owns 16 q rows. KV tile = 32.
__global__ __launch_bounds__(256) void attn_kernel(
    const u16* __restrict__ Q, const u16* __restrict__ K,
    const u16* __restrict__ V, u16* __restrict__ attn) {
  __shared__ u16 Ks[32 * 72];       // [kv][d], row pad 64->72 (2-way banks)
  __shared__ u16 Vt[64 * 40];       // [d][kv], row pad 32->40
  __shared__ u16 Ps[4][16 * 40];    // per-wave P tile [q][kv], pad 32->40

  int t = threadIdx.x;
  int lane = t & 63, wave = t >> 6;
  int g = lane >> 4, c = lane & 15;
  int b = blockIdx.z, h = blockIdx.y, q0 = blockIdx.x * 64;

  const u16* Qh = Q + ((size_t)(b * 16 + h) * 2048) * 64;
  const u16* Kh = K + ((size_t)(b * 16 + h) * 2048) * 64;
  const u16* Vh = V + ((size_t)(b * 16 + h) * 2048) * 64;

  int qw = q0 + wave * 16;
  // Q A-frags held in registers for the whole block
  bf16x8 aq0 = ldfrag(Qh + (size_t)(qw + c) * 64 + g * 8);
  bf16x8 aq1 = ldfrag(Qh + (size_t)(qw + c) * 64 + 32 + g * 8);

  f32x4 o[4] = {};
  float mrow[4], lrow[4];
#pragma unroll
  for (int r = 0; r < 4; ++r) { mrow[r] = -1e30f; lrow[r] = 0.f; }

  int sr = t >> 3;         // 0..31 (kv row)
  int sc = (t & 7) * 8;    // 0..56 (d col)

  for (int kv0 = 0; kv0 < 2048; kv0 += 32) {
    // stage K tile [32][64] (row-major, padded)
    u16x8 kvv = *reinterpret_cast<const u16x8*>(Kh + (size_t)(kv0 + sr) * 64 + sc);
    *reinterpret_cast<u16x8*>(&Ks[sr * 72 + sc]) = kvv;
    // stage V tile transposed: Vt[d][kv]
    u16x8 vv = *reinterpret_cast<const u16x8*>(Vh + (size_t)(kv0 + sr) * 64 + sc);
#pragma unroll
    for (int j = 0; j < 8; ++j) Vt[(sc + j) * 40 + sr] = vv[j];
    __syncthreads();

    // S^tile = Q @ K^T (two 16x16 kv sub-tiles, K-dim 64 = 2 MFMAs each)
    f32x4 s0 = {}, s1 = {};
    s0 = __builtin_amdgcn_mfma_f32_16x16x32_bf16(aq0, ldfrag(&Ks[c * 72 + g * 8]), s0, 0, 0, 0);
    s0 = __builtin_amdgcn_mfma_f32_16x16x32_bf16(aq1, ldfrag(&Ks[c * 72 + 32 + g * 8]), s0, 0, 0, 0);
    s1 = __builtin_amdgcn_mfma_f32_16x16x32_bf16(aq0, ldfrag(&Ks[(16 + c) * 72 + g * 8]), s1, 0, 0, 0);
    s1 = __builtin_amdgcn_mfma_f32_16x16x32_bf16(aq1, ldfrag(&Ks[(16 + c) * 72 + 32 + g * 8]), s1, 0, 0, 0);

    // online softmax; lane holds S[q = g*4+r][kv = c] and [kv = 16+c]
    u16* pw = &Ps[wave][0];
#pragma unroll
    for (int r = 0; r < 4; ++r) {
      float v0 = s0[r] * 0.125f, v1 = s1[r] * 0.125f;
      float tm = fmaxf(v0, v1);
      tm = fmaxf(tm, __shfl_xor(tm, 1));
      tm = fmaxf(tm, __shfl_xor(tm, 2));
      tm = fmaxf(tm, __shfl_xor(tm, 4));
      tm = fmaxf(tm, __shfl_xor(tm, 8));
      float nm = fmaxf(mrow[r], tm);
      float f = __expf(mrow[r] - nm);
      float p0 = __expf(v0 - nm), p1 = __expf(v1 - nm);
      float ts = p0 + p1;
      ts += __shfl_xor(ts, 1); ts += __shfl_xor(ts, 2);
      ts += __shfl_xor(ts, 4); ts += __shfl_xor(ts, 8);
      lrow[r] = lrow[r] * f + ts;
      mrow[r] = nm;
#pragma unroll
      for (int j = 0; j < 4; ++j) o[j][r] *= f;
      pw[(g * 4 + r) * 40 + c] = f2bf(p0);
      pw[(g * 4 + r) * 40 + 16 + c] = f2bf(p1);
    }

    // P (A-frag) @ V : O[q][d] over 4 d-subtiles
    bf16x8 pa = ldfrag(&Ps[wave][c * 40 + g * 8]);
#pragma unroll
    for (int j = 0; j < 4; ++j) {
      bf16x8 bv = ldfrag(&Vt[(16 * j + c) * 40 + g * 8]);
      o[j] = __builtin_amdgcn_mfma_f32_16x16x32_bf16(pa, bv, o[j], 0, 0, 0);
    }
    __syncthreads();
  }

  // epilogue: normalize and write attn[B,S,D] (col = h*64 + d)
#pragma unroll
  for (int j = 0; j < 4; ++j) {
#pragma unroll
    for (int r = 0; r < 4; ++r) {
      int s = qw + g * 4 + r;
      int col = h * 64 + 16 * j + c;
      attn[(size_t)(b * 2048 + s) * 1024 + col] = f2bf(o[j][r] / lrow[r]);
    }
  }
}

extern "C" void kernel_launch(void* const* d_in, const int* in_sizes, int n_in,
                              void* d_out, int out_size, void* d_ws, size_t ws_size,
                              hipStream_t stream) {
  const float* x  = (const float*)d_in[0];
  const float* Wq = (const float*)d_in[1];
  const float* bq = (const float*)d_in[2];
  const float* Wk = (const float*)d_in[3];
  const float* bk = (const float*)d_in[4];
  const float* Wv = (const float*)d_in[5];
  const float* bv = (const float*)d_in[6];
  const float* Wo = (const float*)d_in[7];
  const float* bo = (const float*)d_in[8];
  float* out = (float*)d_out;
  u16* ws = (u16*)d_ws;

  // workspace layout (u16 elems): xb 4M | WT 4x1M | Q 4M | K 4M | V 4M  => 40 MB
  u16* xb    = ws;
  u16* WT    = ws + (size_t)4 * 1024 * 1024;
  u16* Qb    = ws + (size_t)8 * 1024 * 1024;
  u16* Kb    = ws + (size_t)12 * 1024 * 1024;
  u16* Vb    = ws + (size_t)16 * 1024 * 1024;
  u16* attnb = xb;  // xb dead after QKV GEMM; reuse for attn output

  cast_x_kernel<<<2048, 256, 0, stream>>>(x, xb);
  transpose_w_kernel<<<dim3(16, 16, 4), 256, 0, stream>>>(Wq, Wk, Wv, Wo, WT);
  qkv_gemm_kernel<<<dim3(8, 32, 3), 256, 0, stream>>>(xb, WT, bq, bk, bv, Qb, Kb, Vb);
  attn_kernel<<<dim3(32, 16, 2), 256, 0, stream>>>(Qb, Kb, Vb, attnb);
  oproj_kernel<<<dim3(8, 32), 256, 0, stream>>>(attnb, WT + (size_t)3 * 1024 * 1024, bo, out);
}

// Round 2
// 190.923 us; speedup vs baseline: 1.5113x; 1.5113x over previous
//
#include <hip/hip_runtime.h>
#include <stdint.h>

// B=2, S=2048, D=1024, H=16, HD=64
typedef unsigned short u16;
typedef unsigned int u32;
typedef __bf16 bf16x8 __attribute__((ext_vector_type(8)));
typedef float f32x4 __attribute__((ext_vector_type(4)));
typedef unsigned short u16x8 __attribute__((ext_vector_type(8)));
typedef unsigned short u16x4 __attribute__((ext_vector_type(4)));

#define QSCALE 0.1803368801111204f  // 0.125 * log2(e): folded into Wq/bq so softmax uses exp2

static __device__ __forceinline__ u16 f2bf(float f) {
  unsigned u = __builtin_bit_cast(unsigned, f);
  u += 0x7fffu + ((u >> 16) & 1u);   // RNE
  return (u16)(u >> 16);
}

static __device__ __forceinline__ bf16x8 ldfrag(const u16* p) {
  return *reinterpret_cast<const bf16x8*>(p);
}

static __device__ __forceinline__ void gll16(const u16* g, u16* l) {
  __builtin_amdgcn_global_load_lds(
      (const __attribute__((address_space(1))) void*)g,
      (__attribute__((address_space(3))) void*)l, 16, 0, 0);
}

static __device__ __forceinline__ u32 cvt_pk_bf16(float lo, float hi) {
  u32 r;
  asm("v_cvt_pk_bf16_f32 %0, %1, %2" : "=v"(r) : "v"(lo), "v"(hi));
  return r;
}

// ---------------- cast x: fp32 -> bf16, [4096][1024] ----------------
__global__ __launch_bounds__(256) void cast_x_kernel(const float* __restrict__ x,
                                                     u16* __restrict__ xb) {
  int i = (blockIdx.x * 256 + threadIdx.x) * 8;
  const float4* p = reinterpret_cast<const float4*>(x + i);
  float4 a = p[0], b = p[1];
  u16x8 o;
  o[0] = f2bf(a.x); o[1] = f2bf(a.y); o[2] = f2bf(a.z); o[3] = f2bf(a.w);
  o[4] = f2bf(b.x); o[5] = f2bf(b.y); o[6] = f2bf(b.z); o[7] = f2bf(b.w);
  *reinterpret_cast<u16x8*>(xb + i) = o;
}

// -------- transpose + cast W [k][n] fp32 -> Wt [n][k] bf16 (z picks Wq/Wk/Wv/Wo) --------
// Wq is pre-scaled by QSCALE so attention scores arrive in log2 units.
__global__ __launch_bounds__(256) void transpose_w_kernel(
    const float* __restrict__ Wq, const float* __restrict__ Wk,
    const float* __restrict__ Wv, const float* __restrict__ Wo,
    u16* __restrict__ WT) {
  __shared__ float tile[64][65];
  int z = blockIdx.z;
  const float* W = (z == 0) ? Wq : (z == 1) ? Wk : (z == 2) ? Wv : Wo;
  float wscale = (z == 0) ? QSCALE : 1.0f;
  u16* out = WT + (size_t)z * 1024 * 1024;
  int k0 = blockIdx.y * 64, n0 = blockIdx.x * 64;
  int t = threadIdx.x;
  int rr = t >> 4;         // 0..15
  int cc = (t & 15) * 4;   // 0..60
#pragma unroll
  for (int j = 0; j < 4; ++j) {
    int r = rr + 16 * j;
    float4 v = *reinterpret_cast<const float4*>(W + (size_t)(k0 + r) * 1024 + n0 + cc);
    tile[r][cc + 0] = v.x; tile[r][cc + 1] = v.y;
    tile[r][cc + 2] = v.z; tile[r][cc + 3] = v.w;
  }
  __syncthreads();
#pragma unroll
  for (int j = 0; j < 4; ++j) {
    int nl = rr + 16 * j;
    u16x4 o;
#pragma unroll
    for (int i2 = 0; i2 < 4; ++i2) o[i2] = f2bf(tile[cc + i2][nl] * wscale);
    *reinterpret_cast<u16x4*>(out + (size_t)(n0 + nl) * 1024 + k0 + cc) = o;
  }
}

// ---------------- generic bf16 GEMM: C[4096][1024] = A @ Wt^T + bias ----------------
template <int MODE>
static __device__ __forceinline__ void gemm_body(const u16* __restrict__ A,
                                                 const u16* __restrict__ Wt,
                                                 const float* __restrict__ bias,
                                                 float bscale,
                                                 void* __restrict__ Out) {
  __shared__ u16 As[128 * 32];
  __shared__ u16 Bs[128 * 32];
  int t = threadIdx.x;
  int lane = t & 63, wave = t >> 6;
  int g = lane >> 4, c = lane & 15;
  int m0 = blockIdx.y * 128, n0 = blockIdx.x * 128;
  int wm = (wave >> 1) * 64, wn = (wave & 1) * 64;

  f32x4 acc[4][4] = {};

  const u16* Ag = A + (size_t)(m0 + (t >> 2)) * 1024 + (t & 3) * 8;
  const u16* Bg = Wt + (size_t)(n0 + (t >> 2)) * 1024 + (t & 3) * 8;
  u16* Asd = As + t * 8;
  u16* Bsd = Bs + t * 8;

  for (int k0 = 0; k0 < 1024; k0 += 32) {
    gll16(Ag + k0, Asd);
    gll16(Ag + 64 * 1024 + k0, Asd + 64 * 32);
    gll16(Bg + k0, Bsd);
    gll16(Bg + 64 * 1024 + k0, Bsd + 64 * 32);
    __syncthreads();
    bf16x8 af[4], bfr[4];
#pragma unroll
    for (int i = 0; i < 4; ++i) {
      af[i]  = ldfrag(As + (wm + 16 * i + c) * 32 + g * 8);
      bfr[i] = ldfrag(Bs + (wn + 16 * i + c) * 32 + g * 8);
    }
#pragma unroll
    for (int i = 0; i < 4; ++i)
#pragma unroll
      for (int j = 0; j < 4; ++j)
        acc[i][j] = __builtin_amdgcn_mfma_f32_16x16x32_bf16(af[i], bfr[j], acc[i][j], 0, 0, 0);
    __syncthreads();
  }

  if (MODE == 0) {
    u16* out = (u16*)Out;
#pragma unroll
    for (int i = 0; i < 4; ++i) {
      int mb = m0 + wm + 16 * i + g * 4;
#pragma unroll
      for (int j = 0; j < 4; ++j) {
        int n = n0 + wn + 16 * j + c;
        float bv = bias[n] * bscale;
        int h = n >> 6, d = n & 63;
#pragma unroll
        for (int r = 0; r < 4; ++r) {
          int m = mb + r;
          int b = m >> 11, s = m & 2047;   // m = b*2048 + s
          out[((size_t)(b * 16 + h) * 2048 + s) * 64 + d] = f2bf(acc[i][j][r] + bv);
        }
      }
    }
  } else {
    float* out = (float*)Out;
#pragma unroll
    for (int i = 0; i < 4; ++i) {
      int mb = m0 + wm + 16 * i + g * 4;
#pragma unroll
      for (int j = 0; j < 4; ++j) {
        int n = n0 + wn + 16 * j + c;
        float bv = bias[n];
#pragma unroll
        for (int r = 0; r < 4; ++r)
          out[(size_t)(mb + r) * 1024 + n] = acc[i][j][r] + bv;
      }
    }
  }
}

__global__ __launch_bounds__(256) void qkv_gemm_kernel(
    const u16* __restrict__ xb, const u16* __restrict__ WT,
    const float* __restrict__ bq, const float* __restrict__ bk,
    const float* __restrict__ bv,
    u16* __restrict__ Q, u16* __restrict__ K, u16* __restrict__ V) {
  int z = blockIdx.z;
  const u16* Wt = WT + (size_t)z * 1024 * 1024;
  const float* bias = (z == 0) ? bq : (z == 1) ? bk : bv;
  float bscale = (z == 0) ? QSCALE : 1.0f;
  u16* out = (z == 0) ? Q : (z == 1) ? K : V;
  gemm_body<0>(xb, Wt, bias, bscale, out);
}

__global__ __launch_bounds__(256) void oproj_kernel(
    const u16* __restrict__ attnb, const u16* __restrict__ WoT,
    const float* __restrict__ bo, float* __restrict__ out) {
  gemm_body<1>(attnb, WoT, bo, 1.0f, out);
}

// ---------------- flash attention (swapped-QK, frag-native LDS, KVBLK=64) ----------------
// Q,K,V: [B,H,S,HD] bf16 (Q pre-scaled by QSCALE). Output attn: [B,S,D] bf16.
// Block: 4 waves, each owns 16 q rows (64 q rows / block). KV tile = 64, double-buffered.
//
// Kf layout: unit u (16B) = ((t4*2+u)*4+g)*16+c  holds K[16*t4+c][32*u+8*g .. +7]
//   -> QK A-frag read is lane-linear ds_read_b128 (conflict-free, broadcast across waves)
//   -> staged with global_load_lds, permutation applied on the GLOBAL address (rule 21)
// Vf layout: unit = ((m*4+j)*4+g)*16+c holds V[32m+8g+e][16j+c] (PV B-frag lane-linear)
//   -> scatter-written (8x ds_write_b16/row), ~2-way conflicts
// Pf layout: per-wave, unit = (m*4+g)*16+c holds P[q=c][kv=32m+8g+e] (PV A-frag lane-linear)
//   -> written as packed u32 pairs via v_cvt_pk_bf16_f32, same-wave RAW (no barrier)
__global__ __launch_bounds__(256) void attn_kernel(
    const u16* __restrict__ Q, const u16* __restrict__ K,
    const u16* __restrict__ V, u16* __restrict__ attn) {
  __shared__ u16 Kf[2][4096];
  __shared__ u16 Vf[2][4096];
  __shared__ u16 Pf[4][1024];

  const int t = threadIdx.x;
  const int lane = t & 63, w = t >> 6;
  const int g = lane >> 4, c = lane & 15;
  const int b = blockIdx.z, h = blockIdx.y, q0 = blockIdx.x * 64;

  const u16* Qh = Q + ((size_t)(b * 16 + h) * 2048) * 64;
  const u16* Kh = K + ((size_t)(b * 16 + h) * 2048) * 64;
  const u16* Vh = V + ((size_t)(b * 16 + h) * 2048) * 64;

  const int qw = q0 + w * 16;
  // Q B-frags, held in registers for the whole kernel
  bf16x8 qf0 = ldfrag(Qh + (size_t)(qw + c) * 64 + 8 * g);
  bf16x8 qf1 = ldfrag(Qh + (size_t)(qw + c) * 64 + 32 + 8 * g);

  const int rv = t >> 3;            // V stage: kv row 0..31 (and +32)
  const int seg = (t & 7) * 8;      // V stage: d segment

  f32x4 o[4] = {};
  float mrow = -3e38f, lrow = 0.f;

  // ---- prologue: stage tile 0 ----
  {
#pragma unroll
    for (int i = 0; i < 2; ++i) {
      int unit = ((w * 2 + i) << 6) | lane;
      int cc = unit & 15, gg = (unit >> 4) & 3, uu = (unit >> 6) & 1, t4 = (unit >> 7) & 3;
      gll16(Kh + (size_t)(16 * t4 + cc) * 64 + 32 * uu + 8 * gg, &Kf[0][unit * 8]);
    }
    u16x8 v0 = *(const u16x8*)(Vh + (size_t)rv * 64 + seg);
    u16x8 v1 = *(const u16x8*)(Vh + (size_t)(rv + 32) * 64 + seg);
#pragma unroll
    for (int it = 0; it < 2; ++it) {
      u16x8 vv = it ? v1 : v0;
      int r = rv + 32 * it;
      int m = r >> 5, gg = (r >> 3) & 3, e = r & 7;
#pragma unroll
      for (int l = 0; l < 8; ++l) {
        int d = seg + l;
        Vf[0][(((m * 4 + (d >> 4)) * 4 + gg) * 16 + (d & 15)) * 8 + e] = vv[l];
      }
    }
    __syncthreads();
  }

  int cur = 0;
  for (int kv0 = 0; kv0 < 2048; kv0 += 64) {
    const int nxt = kv0 + 64;
    const bool pfch = nxt < 2048;
    u16x8 v0, v1;
    if (pfch) {
      // T14: issue next-tile global loads early; ds_writes after compute
      v0 = *(const u16x8*)(Vh + (size_t)(nxt + rv) * 64 + seg);
      v1 = *(const u16x8*)(Vh + (size_t)(nxt + rv + 32) * 64 + seg);
#pragma unroll
      for (int i = 0; i < 2; ++i) {
        int unit = ((w * 2 + i) << 6) | lane;
        int cc = unit & 15, gg = (unit >> 4) & 3, uu = (unit >> 6) & 1, t4 = (unit >> 7) & 3;
        gll16(Kh + (size_t)(nxt + 16 * t4 + cc) * 64 + 32 * uu + 8 * gg,
              &Kf[cur ^ 1][unit * 8]);
      }
    }

    // ---- swapped QK^T: st[t4] = K(16 kv) . Q^T -> S^T[kv][q], q = c per lane ----
    f32x4 st[4];
#pragma unroll
    for (int t4 = 0; t4 < 4; ++t4) {
      f32x4 acc = {};
      acc = __builtin_amdgcn_mfma_f32_16x16x32_bf16(
          ldfrag(&Kf[cur][((t4 * 2 + 0) * 4 + g) * 128 + c * 8]), qf0, acc, 0, 0, 0);
      acc = __builtin_amdgcn_mfma_f32_16x16x32_bf16(
          ldfrag(&Kf[cur][((t4 * 2 + 1) * 4 + g) * 128 + c * 8]), qf1, acc, 0, 0, 0);
      st[t4] = acc;
    }

    // ---- online softmax over 64-kv tile (scores already in log2 units) ----
    float tm = st[0][0];
#pragma unroll
    for (int t4 = 0; t4 < 4; ++t4)
#pragma unroll
      for (int r = 0; r < 4; ++r) tm = fmaxf(tm, st[t4][r]);
    tm = fmaxf(tm, __shfl_xor(tm, 16));
    tm = fmaxf(tm, __shfl_xor(tm, 32));
    const bool grow = __any(tm > mrow);   // wave-uniform
    float nm = grow ? fmaxf(mrow, tm) : mrow;
    float ts = 0.f;
#pragma unroll
    for (int t4 = 0; t4 < 4; ++t4)
#pragma unroll
      for (int r = 0; r < 4; ++r) {
        float p = exp2f(st[t4][r] - nm);
        st[t4][r] = p;
        ts += p;
      }
    ts += __shfl_xor(ts, 16);
    ts += __shfl_xor(ts, 32);
    if (grow) {
      float f = exp2f(mrow - nm);
      lrow = lrow * f + ts;
      mrow = nm;
#pragma unroll
      for (int r = 0; r < 4; ++r) {
        float fr = __shfl(f, 4 * g + r);   // f lives at lanes indexed by q=c
#pragma unroll
        for (int j = 0; j < 4; ++j) o[j][r] *= fr;
      }
    } else {
      lrow += ts;
    }

    // ---- pack P into per-wave A-frag layout (no barrier: same-wave RAW) ----
    u32* pd = (u32*)&Pf[w][0];
#pragma unroll
    for (int t4 = 0; t4 < 4; ++t4) {
      u32 w0 = cvt_pk_bf16(st[t4][0], st[t4][1]);
      u32 w1 = cvt_pk_bf16(st[t4][2], st[t4][3]);
      int m = t4 >> 1, gp = (2 * t4 + (g >> 1)) & 3;
      int base = ((m * 4 + gp) * 16 + c) * 4 + 2 * (g & 1);
      pd[base] = w0;
      pd[base + 1] = w1;
    }

    // ---- PV: O[q][d] += P . V ----
#pragma unroll
    for (int m = 0; m < 2; ++m) {
      bf16x8 pa = ldfrag(&Pf[w][((m * 4 + g) * 16 + c) * 8]);
#pragma unroll
      for (int j = 0; j < 4; ++j) {
        bf16x8 vb = ldfrag(&Vf[cur][((m * 4 + j) * 4 + g) * 128 + c * 8]);
        o[j] = __builtin_amdgcn_mfma_f32_16x16x32_bf16(pa, vb, o[j], 0, 0, 0);
      }
    }

    if (pfch) {
#pragma unroll
      for (int it = 0; it < 2; ++it) {
        u16x8 vv = it ? v1 : v0;
        int r = rv + 32 * it;
        int m = r >> 5, gg = (r >> 3) & 3, e = r & 7;
#pragma unroll
        for (int l = 0; l < 8; ++l) {
          int d = seg + l;
          Vf[cur ^ 1][(((m * 4 + (d >> 4)) * 4 + gg) * 16 + (d & 15)) * 8 + e] = vv[l];
        }
      }
    }
    __syncthreads();
    cur ^= 1;
  }

  // ---- epilogue: normalize, write attn[B,S,D] (O lane layout: q=4g+r, d=16j+c) ----
  float rinv[4];
#pragma unroll
  for (int r = 0; r < 4; ++r) rinv[r] = 1.f / __shfl(lrow, 4 * g + r);
#pragma unroll
  for (int j = 0; j < 4; ++j)
#pragma unroll
    for (int r = 0; r < 4; ++r) {
      int s = qw + 4 * g + r;
      attn[(size_t)(b * 2048 + s) * 1024 + h * 64 + 16 * j + c] = f2bf(o[j][r] * rinv[r]);
    }
}

extern "C" void kernel_launch(void* const* d_in, const int* in_sizes, int n_in,
                              void* d_out, int out_size, void* d_ws, size_t ws_size,
                              hipStream_t stream) {
  const float* x  = (const float*)d_in[0];
  const float* Wq = (const float*)d_in[1];
  const float* bq = (const float*)d_in[2];
  const float* Wk = (const float*)d_in[3];
  const float* bk = (const float*)d_in[4];
  const float* Wv = (const float*)d_in[5];
  const float* bv = (const float*)d_in[6];
  const float* Wo = (const float*)d_in[7];
  const float* bo = (const float*)d_in[8];
  float* out = (float*)d_out;
  u16* ws = (u16*)d_ws;

  // workspace layout (u16 elems): xb 4M | WT 4x1M | Q 4M | K 4M | V 4M  => 40 MB
  u16* xb    = ws;
  u16* WT    = ws + (size_t)4 * 1024 * 1024;
  u16* Qb    = ws + (size_t)8 * 1024 * 1024;
  u16* Kb    = ws + (size_t)12 * 1024 * 1024;
  u16* Vb    = ws + (size_t)16 * 1024 * 1024;
  u16* attnb = xb;  // xb dead after QKV GEMM; reuse for attn output

  cast_x_kernel<<<2048, 256, 0, stream>>>(x, xb);
  transpose_w_kernel<<<dim3(16, 16, 4), 256, 0, stream>>>(Wq, Wk, Wv, Wo, WT);
  qkv_gemm_kernel<<<dim3(8, 32, 3), 256, 0, stream>>>(xb, WT, bq, bk, bv, Qb, Kb, Vb);
  attn_kernel<<<dim3(32, 16, 2), 256, 0, stream>>>(Qb, Kb, Vb, attnb);
  oproj_kernel<<<dim3(8, 32), 256, 0, stream>>>(attnb, WT + (size_t)3 * 1024 * 1024, bo, out);
}

// Round 3
// 158.447 us; speedup vs baseline: 1.8211x; 1.2050x over previous
//
#include <hip/hip_runtime.h>
#include <stdint.h>

// B=2, S=2048, D=1024, H=16, HD=64
typedef unsigned short u16;
typedef unsigned int u32;
typedef __bf16 bf16x8 __attribute__((ext_vector_type(8)));
typedef float f32x4 __attribute__((ext_vector_type(4)));
typedef unsigned short u16x8 __attribute__((ext_vector_type(8)));
typedef unsigned short u16x4 __attribute__((ext_vector_type(4)));

#define QSCALE 0.1803368801111204f  // 0.125 * log2(e): folded into Wq/bq so softmax uses exp2

static __device__ __forceinline__ u16 f2bf(float f) {
  unsigned u = __builtin_bit_cast(unsigned, f);
  u += 0x7fffu + ((u >> 16) & 1u);   // RNE
  return (u16)(u >> 16);
}

static __device__ __forceinline__ bf16x8 ldfrag(const u16* p) {
  return *reinterpret_cast<const bf16x8*>(p);
}

static __device__ __forceinline__ void gll16(const u16* g, u16* l) {
  __builtin_amdgcn_global_load_lds(
      (const __attribute__((address_space(1))) void*)g,
      (__attribute__((address_space(3))) void*)l, 16, 0, 0);
}

static __device__ __forceinline__ u32 cvt_pk_bf16(float lo, float hi) {
  u32 r;
  asm("v_cvt_pk_bf16_f32 %0, %1, %2" : "=v"(r) : "v"(lo), "v"(hi));
  return r;
}

// V-frag LDS swizzle: XOR bits {3,6,7} of the 16B-unit index into bits {0,2:1}.
// Involution; write-side spreads the 8-way-conflicting slots across all 32 banks,
// read-side stays a permutation of each wave's contiguous 1KB (conflict-free).
static __device__ __forceinline__ int vswz(int L) {
  return L ^ ((((L >> 6) & 3) << 1) | ((L >> 3) & 1));
}

// ---------------- cast x: fp32 -> bf16, [4096][1024] ----------------
__global__ __launch_bounds__(256) void cast_x_kernel(const float* __restrict__ x,
                                                     u16* __restrict__ xb) {
  int i = (blockIdx.x * 256 + threadIdx.x) * 8;
  const float4* p = reinterpret_cast<const float4*>(x + i);
  float4 a = p[0], b = p[1];
  u16x8 o;
  o[0] = f2bf(a.x); o[1] = f2bf(a.y); o[2] = f2bf(a.z); o[3] = f2bf(a.w);
  o[4] = f2bf(b.x); o[5] = f2bf(b.y); o[6] = f2bf(b.z); o[7] = f2bf(b.w);
  *reinterpret_cast<u16x8*>(xb + i) = o;
}

// -------- transpose + cast W [k][n] fp32 -> Wt [n][k] bf16 (z picks Wq/Wk/Wv/Wo) --------
__global__ __launch_bounds__(256) void transpose_w_kernel(
    const float* __restrict__ Wq, const float* __restrict__ Wk,
    const float* __restrict__ Wv, const float* __restrict__ Wo,
    u16* __restrict__ WT) {
  __shared__ float tile[64][65];
  int z = blockIdx.z;
  const float* W = (z == 0) ? Wq : (z == 1) ? Wk : (z == 2) ? Wv : Wo;
  float wscale = (z == 0) ? QSCALE : 1.0f;
  u16* out = WT + (size_t)z * 1024 * 1024;
  int k0 = blockIdx.y * 64, n0 = blockIdx.x * 64;
  int t = threadIdx.x;
  int rr = t >> 4;         // 0..15
  int cc = (t & 15) * 4;   // 0..60
#pragma unroll
  for (int j = 0; j < 4; ++j) {
    int r = rr + 16 * j;
    float4 v = *reinterpret_cast<const float4*>(W + (size_t)(k0 + r) * 1024 + n0 + cc);
    tile[r][cc + 0] = v.x; tile[r][cc + 1] = v.y;
    tile[r][cc + 2] = v.z; tile[r][cc + 3] = v.w;
  }
  __syncthreads();
#pragma unroll
  for (int j = 0; j < 4; ++j) {
    int nl = rr + 16 * j;
    u16x4 o;
#pragma unroll
    for (int i2 = 0; i2 < 4; ++i2) o[i2] = f2bf(tile[cc + i2][nl] * wscale);
    *reinterpret_cast<u16x4*>(out + (size_t)(n0 + nl) * 1024 + k0 + cc) = o;
  }
}

// ---------------- generic bf16 GEMM: C[4096][1024] = A @ Wt^T + bias ----------------
template <int MODE>
static __device__ __forceinline__ void gemm_body(const u16* __restrict__ A,
                                                 const u16* __restrict__ Wt,
                                                 const float* __restrict__ bias,
                                                 float bscale,
                                                 void* __restrict__ Out) {
  __shared__ u16 As[128 * 32];
  __shared__ u16 Bs[128 * 32];
  int t = threadIdx.x;
  int lane = t & 63, wave = t >> 6;
  int g = lane >> 4, c = lane & 15;
  int m0 = blockIdx.y * 128, n0 = blockIdx.x * 128;
  int wm = (wave >> 1) * 64, wn = (wave & 1) * 64;

  f32x4 acc[4][4] = {};

  const u16* Ag = A + (size_t)(m0 + (t >> 2)) * 1024 + (t & 3) * 8;
  const u16* Bg = Wt + (size_t)(n0 + (t >> 2)) * 1024 + (t & 3) * 8;
  u16* Asd = As + t * 8;
  u16* Bsd = Bs + t * 8;

  for (int k0 = 0; k0 < 1024; k0 += 32) {
    gll16(Ag + k0, Asd);
    gll16(Ag + 64 * 1024 + k0, Asd + 64 * 32);
    gll16(Bg + k0, Bsd);
    gll16(Bg + 64 * 1024 + k0, Bsd + 64 * 32);
    __syncthreads();
    bf16x8 af[4], bfr[4];
#pragma unroll
    for (int i = 0; i < 4; ++i) {
      af[i]  = ldfrag(As + (wm + 16 * i + c) * 32 + g * 8);
      bfr[i] = ldfrag(Bs + (wn + 16 * i + c) * 32 + g * 8);
    }
#pragma unroll
    for (int i = 0; i < 4; ++i)
#pragma unroll
      for (int j = 0; j < 4; ++j)
        acc[i][j] = __builtin_amdgcn_mfma_f32_16x16x32_bf16(af[i], bfr[j], acc[i][j], 0, 0, 0);
    __syncthreads();
  }

  if (MODE == 0) {
    u16* out = (u16*)Out;
#pragma unroll
    for (int i = 0; i < 4; ++i) {
      int mb = m0 + wm + 16 * i + g * 4;
#pragma unroll
      for (int j = 0; j < 4; ++j) {
        int n = n0 + wn + 16 * j + c;
        float bv = bias[n] * bscale;
        int h = n >> 6, d = n & 63;
#pragma unroll
        for (int r = 0; r < 4; ++r) {
          int m = mb + r;
          int b = m >> 11, s = m & 2047;   // m = b*2048 + s
          out[((size_t)(b * 16 + h) * 2048 + s) * 64 + d] = f2bf(acc[i][j][r] + bv);
        }
      }
    }
  } else {
    float* out = (float*)Out;
#pragma unroll
    for (int i = 0; i < 4; ++i) {
      int mb = m0 + wm + 16 * i + g * 4;
#pragma unroll
      for (int j = 0; j < 4; ++j) {
        int n = n0 + wn + 16 * j + c;
        float bv = bias[n];
#pragma unroll
        for (int r = 0; r < 4; ++r)
          out[(size_t)(mb + r) * 1024 + n] = acc[i][j][r] + bv;
      }
    }
  }
}

__global__ __launch_bounds__(256) void qkv_gemm_kernel(
    const u16* __restrict__ xb, const u16* __restrict__ WT,
    const float* __restrict__ bq, const float* __restrict__ bk,
    const float* __restrict__ bv,
    u16* __restrict__ Q, u16* __restrict__ K, u16* __restrict__ V) {
  int z = blockIdx.z;
  const u16* Wt = WT + (size_t)z * 1024 * 1024;
  const float* bias = (z == 0) ? bq : (z == 1) ? bk : bv;
  float bscale = (z == 0) ? QSCALE : 1.0f;
  u16* out = (z == 0) ? Q : (z == 1) ? K : V;
  gemm_body<0>(xb, Wt, bias, bscale, out);
}

__global__ __launch_bounds__(256) void oproj_kernel(
    const u16* __restrict__ attnb, const u16* __restrict__ WoT,
    const float* __restrict__ bo, float* __restrict__ out) {
  gemm_body<1>(attnb, WoT, bo, 1.0f, out);
}

// ---------------- flash attention (swapped-QK, frag-native LDS, KVBLK=64) ----------------
__global__ __launch_bounds__(256) void attn_kernel(
    const u16* __restrict__ Q, const u16* __restrict__ K,
    const u16* __restrict__ V, u16* __restrict__ attn) {
  __shared__ u16 Kf[2][4096];
  __shared__ u16 Vf[2][4096];
  __shared__ u16 Pf[4][1024];

  const int t = threadIdx.x;
  const int lane = t & 63, w = t >> 6;
  const int g = lane >> 4, c = lane & 15;
  const int b = blockIdx.z, h = blockIdx.y, q0 = blockIdx.x * 64;

  const u16* Qh = Q + ((size_t)(b * 16 + h) * 2048) * 64;
  const u16* Kh = K + ((size_t)(b * 16 + h) * 2048) * 64;
  const u16* Vh = V + ((size_t)(b * 16 + h) * 2048) * 64;

  const int qw = q0 + w * 16;
  // Q B-frags, held in registers for the whole kernel
  bf16x8 qf0 = ldfrag(Qh + (size_t)(qw + c) * 64 + 8 * g);
  bf16x8 qf1 = ldfrag(Qh + (size_t)(qw + c) * 64 + 32 + 8 * g);

  const int rv = t >> 3;            // V stage: kv row 0..31 (and +32)
  const int seg = (t & 7) * 8;      // V stage: d segment

  // loop-invariant swizzled V-write offsets (u16 units)
  int vwoff[2][8];
#pragma unroll
  for (int it = 0; it < 2; ++it) {
    int r = rv + 32 * it;
    int m = r >> 5, gg = (r >> 3) & 3, e = r & 7;
#pragma unroll
    for (int l = 0; l < 8; ++l) {
      int d = seg + l;
      int L = ((m * 4 + (d >> 4)) * 4 + gg) * 16 + (d & 15);
      vwoff[it][l] = vswz(L) * 8 + e;
    }
  }

  f32x4 o[4] = {};
  float mrow = -3e38f, lrow = 0.f;

  // ---- prologue: stage tile 0 ----
  {
#pragma unroll
    for (int i = 0; i < 2; ++i) {
      int unit = ((w * 2 + i) << 6) | lane;
      int cc = unit & 15, gg = (unit >> 4) & 3, uu = (unit >> 6) & 1, t4 = (unit >> 7) & 3;
      gll16(Kh + (size_t)(16 * t4 + cc) * 64 + 32 * uu + 8 * gg, &Kf[0][unit * 8]);
    }
    u16x8 v0 = *(const u16x8*)(Vh + (size_t)rv * 64 + seg);
    u16x8 v1 = *(const u16x8*)(Vh + (size_t)(rv + 32) * 64 + seg);
#pragma unroll
    for (int l = 0; l < 8; ++l) Vf[0][vwoff[0][l]] = v0[l];
#pragma unroll
    for (int l = 0; l < 8; ++l) Vf[0][vwoff[1][l]] = v1[l];
    __syncthreads();
  }

  int cur = 0;
  for (int kv0 = 0; kv0 < 2048; kv0 += 64) {
    const int nxt = kv0 + 64;
    const bool pfch = nxt < 2048;
    u16x8 v0, v1;
    if (pfch) {
      // T14: issue next-tile global loads early; ds_writes after compute
      v0 = *(const u16x8*)(Vh + (size_t)(nxt + rv) * 64 + seg);
      v1 = *(const u16x8*)(Vh + (size_t)(nxt + rv + 32) * 64 + seg);
#pragma unroll
      for (int i = 0; i < 2; ++i) {
        int unit = ((w * 2 + i) << 6) | lane;
        int cc = unit & 15, gg = (unit >> 4) & 3, uu = (unit >> 6) & 1, t4 = (unit >> 7) & 3;
        gll16(Kh + (size_t)(nxt + 16 * t4 + cc) * 64 + 32 * uu + 8 * gg,
              &Kf[cur ^ 1][unit * 8]);
      }
    }

    // ---- swapped QK^T: st[t4] = K(16 kv) . Q^T -> S^T[kv][q], q = c per lane ----
    f32x4 st[4];
#pragma unroll
    for (int t4 = 0; t4 < 4; ++t4) {
      f32x4 acc = {};
      acc = __builtin_amdgcn_mfma_f32_16x16x32_bf16(
          ldfrag(&Kf[cur][((t4 * 2 + 0) * 4 + g) * 128 + c * 8]), qf0, acc, 0, 0, 0);
      acc = __builtin_amdgcn_mfma_f32_16x16x32_bf16(
          ldfrag(&Kf[cur][((t4 * 2 + 1) * 4 + g) * 128 + c * 8]), qf1, acc, 0, 0, 0);
      st[t4] = acc;
    }

    // ---- online softmax over 64-kv tile (scores already in log2 units) ----
    float tmq[4];
#pragma unroll
    for (int t4 = 0; t4 < 4; ++t4)
      tmq[t4] = fmaxf(fmaxf(st[t4][0], st[t4][1]), fmaxf(st[t4][2], st[t4][3]));
    float tm = fmaxf(fmaxf(tmq[0], tmq[1]), fmaxf(tmq[2], tmq[3]));
    tm = fmaxf(tm, __shfl_xor(tm, 16));
    tm = fmaxf(tm, __shfl_xor(tm, 32));
    // T13 defer-max: only rescale when the max grew by >8 (log2 units; P <= 2^8)
    const bool grow = __any(tm > mrow + 8.0f);
    float nm = grow ? fmaxf(mrow, tm) : mrow;
    float tsq[4];
#pragma unroll
    for (int t4 = 0; t4 < 4; ++t4) {
#pragma unroll
      for (int r = 0; r < 4; ++r) st[t4][r] = exp2f(st[t4][r] - nm);
      tsq[t4] = (st[t4][0] + st[t4][1]) + (st[t4][2] + st[t4][3]);
    }
    float ts = (tsq[0] + tsq[1]) + (tsq[2] + tsq[3]);
    ts += __shfl_xor(ts, 16);
    ts += __shfl_xor(ts, 32);
    if (grow) {
      float f = exp2f(mrow - nm);
      lrow = lrow * f + ts;
      mrow = nm;
#pragma unroll
      for (int r = 0; r < 4; ++r) {
        float fr = __shfl(f, 4 * g + r);   // f lives at lanes indexed by q=c
#pragma unroll
        for (int j = 0; j < 4; ++j) o[j][r] *= fr;
      }
    } else {
      lrow += ts;
    }

    // ---- pack P into per-wave A-frag layout (no barrier: same-wave RAW) ----
    u32* pd = (u32*)&Pf[w][0];
#pragma unroll
    for (int t4 = 0; t4 < 4; ++t4) {
      u32 w0 = cvt_pk_bf16(st[t4][0], st[t4][1]);
      u32 w1 = cvt_pk_bf16(st[t4][2], st[t4][3]);
      int m = t4 >> 1, gp = (2 * t4 + (g >> 1)) & 3;
      int base = ((m * 4 + gp) * 16 + c) * 4 + 2 * (g & 1);
      pd[base] = w0;
      pd[base + 1] = w1;
    }

    // ---- PV: O[q][d] += P . V ----
#pragma unroll
    for (int m = 0; m < 2; ++m) {
      bf16x8 pa = ldfrag(&Pf[w][((m * 4 + g) * 16 + c) * 8]);
#pragma unroll
      for (int j = 0; j < 4; ++j) {
        bf16x8 vb = ldfrag(&Vf[cur][vswz(((m * 4 + j) * 4 + g) * 16 + c) * 8]);
        o[j] = __builtin_amdgcn_mfma_f32_16x16x32_bf16(pa, vb, o[j], 0, 0, 0);
      }
    }

    if (pfch) {
#pragma unroll
      for (int l = 0; l < 8; ++l) Vf[cur ^ 1][vwoff[0][l]] = v0[l];
#pragma unroll
      for (int l = 0; l < 8; ++l) Vf[cur ^ 1][vwoff[1][l]] = v1[l];
    }
    __syncthreads();
    cur ^= 1;
  }

  // ---- epilogue: normalize, write attn[B,S,D] (O lane layout: q=4g+r, d=16j+c) ----
  float rinv[4];
#pragma unroll
  for (int r = 0; r < 4; ++r) rinv[r] = 1.f / __shfl(lrow, 4 * g + r);
#pragma unroll
  for (int j = 0; j < 4; ++j)
#pragma unroll
    for (int r = 0; r < 4; ++r) {
      int s = qw + 4 * g + r;
      attn[(size_t)(b * 2048 + s) * 1024 + h * 64 + 16 * j + c] = f2bf(o[j][r] * rinv[r]);
    }
}

extern "C" void kernel_launch(void* const* d_in, const int* in_sizes, int n_in,
                              void* d_out, int out_size, void* d_ws, size_t ws_size,
                              hipStream_t stream) {
  const float* x  = (const float*)d_in[0];
  const float* Wq = (const float*)d_in[1];
  const float* bq = (const float*)d_in[2];
  const float* Wk = (const float*)d_in[3];
  const float* bk = (const float*)d_in[4];
  const float* Wv = (const float*)d_in[5];
  const float* bv = (const float*)d_in[6];
  const float* Wo = (const float*)d_in[7];
  const float* bo = (const float*)d_in[8];
  float* out = (float*)d_out;
  u16* ws = (u16*)d_ws;

  // workspace layout (u16 elems): xb 4M | WT 4x1M | Q 4M | K 4M | V 4M  => 40 MB
  u16* xb    = ws;
  u16* WT    = ws + (size_t)4 * 1024 * 1024;
  u16* Qb    = ws + (size_t)8 * 1024 * 1024;
  u16* Kb    = ws + (size_t)12 * 1024 * 1024;
  u16* Vb    = ws + (size_t)16 * 1024 * 1024;
  u16* attnb = xb;  // xb dead after QKV GEMM; reuse for attn output

  cast_x_kernel<<<2048, 256, 0, stream>>>(x, xb);
  transpose_w_kernel<<<dim3(16, 16, 4), 256, 0, stream>>>(Wq, Wk, Wv, Wo, WT);
  qkv_gemm_kernel<<<dim3(8, 32, 3), 256, 0, stream>>>(xb, WT, bq, bk, bv, Qb, Kb, Vb);
  attn_kernel<<<dim3(32, 16, 2), 256, 0, stream>>>(Qb, Kb, Vb, attnb);
  oproj_kernel<<<dim3(8, 32), 256, 0, stream>>>(attnb, WT + (size_t)3 * 1024 * 1024, bo, out);
}